// Round 8
// baseline (330.052 us; speedup 1.0000x reference)
//
#include <hip/hip_runtime.h>
#include <math.h>

#define DM    768
#define NH    12
#define DKH   64
#define DFF   3072
#define BATCH 2
#define SLEN  2048
#define MTOT  4096
#define LNEPS 1e-6f
#define QSCALE 0.18033688011112042f   // 0.125 * log2(e): softmax in exp2 domain

typedef unsigned short u16;
typedef __attribute__((ext_vector_type(8))) short bf16x8;   // MFMA A/B frag (4 VGPRs)
typedef __attribute__((ext_vector_type(4))) float f32x4;    // MFMA C/D frag
typedef __attribute__((ext_vector_type(4))) unsigned short us4;

__device__ __forceinline__ u16 f2bf(float f) {              // RNE float->bf16
    union { float f; unsigned int u; } v; v.f = f;
    unsigned int r = v.u + 0x7FFFu + ((v.u >> 16) & 1u);
    return (u16)(r >> 16);
}

// pack two floats -> two bf16 (TRUNCATED) in one u32 via v_perm_b32
__device__ __forceinline__ unsigned pk2bf_t(float lo, float hi) {
    union { float f; unsigned u; } a, b;
    a.f = lo; b.f = hi;
    return __builtin_amdgcn_perm(b.u, a.u, 0x07060302u);
}

// async global->LDS, 16 B per lane. LDS dest = wave-uniform base + lane*16.
__device__ __forceinline__ void gld16(const void* g, void* lds) {
    __builtin_amdgcn_global_load_lds(
        (const __attribute__((address_space(1))) unsigned int*)(unsigned long long)g,
        (__attribute__((address_space(3))) unsigned int*)(unsigned int)(unsigned long long)lds,
        16, 0, 0);
}

// ---------------------------------------------------------------------------
// LayerNorm body: fp32 in -> bf16 out, 256 threads, 3 elems each.
// Optional fused epilogue: out2[row] = x[row] + b2 (fp32).
// ---------------------------------------------------------------------------
__device__ __forceinline__ void ln_body(const float* __restrict__ x,
                                        u16* __restrict__ out,
                                        const float* __restrict__ alpha_p,
                                        const float* __restrict__ beta_p,
                                        const float* __restrict__ b2,
                                        float* __restrict__ out2, int row) {
    const float* xr = x + (size_t)row * DM;
    int t = threadIdx.x;
    float v0 = xr[t], v1 = xr[t + 256], v2 = xr[t + 512];
    float s = v0 + v1 + v2;
    #pragma unroll
    for (int off = 32; off > 0; off >>= 1) s += __shfl_down(s, off);
    __shared__ float red[4], red2[4];
    int wv = t >> 6, ln = t & 63;
    if (ln == 0) red[wv] = s;
    __syncthreads();
    float mean = (red[0] + red[1] + red[2] + red[3]) * (1.0f / 768.0f);
    float d0 = v0 - mean, d1 = v1 - mean, d2 = v2 - mean;
    float sq = d0 * d0 + d1 * d1 + d2 * d2;
    #pragma unroll
    for (int off = 32; off > 0; off >>= 1) sq += __shfl_down(sq, off);
    if (ln == 0) red2[wv] = sq;
    __syncthreads();
    float var = (red2[0] + red2[1] + red2[2] + red2[3]) * (1.0f / 767.0f); // ddof=1
    float scale = alpha_p[0] / (sqrtf(var) + LNEPS);
    float bias = beta_p[0];
    u16* orow = out + (size_t)row * DM;
    orow[t]       = f2bf(d0 * scale + bias);
    orow[t + 256] = f2bf(d1 * scale + bias);
    orow[t + 512] = f2bf(d2 * scale + bias);
    if (out2) {
        float* o2 = out2 + (size_t)row * DM;
        o2[t]       = v0 + b2[t];
        o2[t + 256] = v1 + b2[t + 256];
        o2[t + 512] = v2 + b2[t + 512];
    }
}

__global__ __launch_bounds__(256) void ln_kernel(const float* __restrict__ x,
                                                 u16* __restrict__ out,
                                                 const float* __restrict__ alpha_p,
                                                 const float* __restrict__ beta_p,
                                                 const float* __restrict__ b2,
                                                 float* __restrict__ out2) {
    ln_body(x, out, alpha_p, beta_p, b2, out2, blockIdx.x);
}

// ---------------------------------------------------------------------------
// Weight cast+transpose body: src[R][C] fp32 -> dst[C][R] bf16, 32x32 tiles.
// ---------------------------------------------------------------------------
__device__ __forceinline__ void wcast_body(const float* __restrict__ src,
                                           u16* __restrict__ dst,
                                           int R, int C, int bx, int by) {
    __shared__ float tile[32][33];
    int t = threadIdx.x, tx = t & 31, ty = t >> 5;
    int r0 = by * 32, c0 = bx * 32;
    #pragma unroll
    for (int p = 0; p < 4; p++)
        tile[ty + p * 8][tx] = src[(size_t)(r0 + ty + p * 8) * C + c0 + tx];
    __syncthreads();
    #pragma unroll
    for (int p = 0; p < 4; p++)
        dst[(size_t)(c0 + ty + p * 8) * R + r0 + tx] = f2bf(tile[tx][ty + p * 8]);
}

// ---------------------------------------------------------------------------
// Fused prep: blocks 0..4095 = LN1 rows; rest = all six weight-cast tiles.
// ---------------------------------------------------------------------------
__global__ __launch_bounds__(256) void prep_kernel(
        const float* __restrict__ x, u16* __restrict__ h,
        const float* __restrict__ ln1a, const float* __restrict__ ln1b,
        const float* __restrict__ wq, const float* __restrict__ wk,
        const float* __restrict__ wv, const float* __restrict__ wo,
        const float* __restrict__ w1, const float* __restrict__ w2,
        u16* __restrict__ wqT, u16* __restrict__ wkT, u16* __restrict__ wvT,
        u16* __restrict__ woT, u16* __restrict__ w1T, u16* __restrict__ w2T) {
    int bid = blockIdx.x;
    if (bid < MTOT) {
        ln_body(x, h, ln1a, ln1b, nullptr, nullptr, bid);
        return;
    }
    bid -= MTOT;
    const float* src; u16* dst; int R, C, bx, by;
    if (bid < 2304) {
        int j = bid / 576, tix = bid % 576;
        R = 768; C = 768; bx = tix % 24; by = tix / 24;
        src = (j == 0) ? wq : (j == 1) ? wk : (j == 2) ? wv : wo;
        dst = (j == 0) ? wqT : (j == 1) ? wkT : (j == 2) ? wvT : woT;
    } else if (bid < 4608) {
        int tix = bid - 2304;
        R = 768; C = 3072; bx = tix % 96; by = tix / 96;
        src = w1; dst = w1T;
    } else {
        int tix = bid - 4608;
        R = 3072; C = 768; bx = tix % 24; by = tix / 24;
        src = w2; dst = w2T;
    }
    wcast_body(src, dst, R, C, bx, by);
}

// ---------------------------------------------------------------------------
// bf16 MFMA GEMM, 64x64 tile, BK=32, double-buffered, XOR-swizzled LDS.
// 4 waves 2x2, each wave 32x32 (2x2 MFMA). 16 KB LDS, low VGPR -> high
// occupancy; small tiles give 4x more blocks (TLP) for K=768 shapes where
// 128-tiles left the grid at ~2 blocks/CU.
// EPI: 0 = bf16 out *scale, 1 = bf16 relu, 2 = fp32 + resid,
//      3 = bf16 transposed (dst[n][m]), 5 = fp32 atomicAdd (split-K)
// ---------------------------------------------------------------------------
template<int EPI>
__device__ __forceinline__ void gemm64_core(const u16* __restrict__ A,
                                            const u16* __restrict__ Wt,
                                            const float* __restrict__ bias,
                                            const float* __restrict__ resid,
                                            void* __restrict__ Cout,
                                            int M, int N, int Kstride, int Kloop,
                                            float scale, int bm, int bn) {
    __shared__ __align__(16) u16 As[2][64 * 32];
    __shared__ __align__(16) u16 Bs[2][64 * 32];
    int t = threadIdx.x, ln = t & 63, w = t >> 6;
    int wm = w >> 1, wn = w & 1;
    int quad = ln >> 4, col = ln & 15;
    int m0 = bm * 64, n0 = bn * 64;

    f32x4 acc[2][2];
    const f32x4 zero = {0.f, 0.f, 0.f, 0.f};
    #pragma unroll
    for (int i = 0; i < 2; i++)
        #pragma unroll
        for (int j = 0; j < 2; j++) acc[i][j] = zero;

    int st_ch = (((ln & 3) ^ ((ln >> 3) & 3))) * 8;
    const u16* Ag = A  + (size_t)(m0 + 16 * w + (ln >> 2)) * Kstride + st_ch;
    const u16* Bg = Wt + (size_t)(n0 + 16 * w + (ln >> 2)) * Kstride + st_ch;
    gld16(Ag, As[0] + w * 512);
    gld16(Bg, Bs[0] + w * 512);
    __syncthreads();

    int rch = (quad ^ ((col >> 1) & 3)) * 8;

    for (int k0 = 0; k0 < Kloop; k0 += 32) {
        int cur = (k0 >> 5) & 1, nxt = cur ^ 1;
        if (k0 + 32 < Kloop) {
            gld16(Ag + k0 + 32, As[nxt] + w * 512);
            gld16(Bg + k0 + 32, Bs[nxt] + w * 512);
        }
        bf16x8 af[2], bfr[2];
        #pragma unroll
        for (int i = 0; i < 2; i++)
            af[i] = *(const bf16x8*)&As[cur][(wm * 32 + i * 16 + col) * 32 + rch];
        #pragma unroll
        for (int j = 0; j < 2; j++)
            bfr[j] = *(const bf16x8*)&Bs[cur][(wn * 32 + j * 16 + col) * 32 + rch];
        #pragma unroll
        for (int i = 0; i < 2; i++)
            #pragma unroll
            for (int j = 0; j < 2; j++)
                acc[i][j] = __builtin_amdgcn_mfma_f32_16x16x32_bf16(af[i], bfr[j], acc[i][j], 0, 0, 0);
        __syncthreads();
    }

    #pragma unroll
    for (int i = 0; i < 2; i++) {
        int mb = m0 + wm * 32 + i * 16 + quad * 4;
        #pragma unroll
        for (int j = 0; j < 2; j++) {
            int n = n0 + wn * 32 + j * 16 + col;
            if (EPI == 0 || EPI == 1) {
                float bs = bias[n];
                u16* Cb = (u16*)Cout;
                #pragma unroll
                for (int r = 0; r < 4; r++) {
                    float f = (acc[i][j][r] + bs) * ((EPI == 0) ? scale : 1.0f);
                    if (EPI == 1) f = fmaxf(f, 0.f);
                    Cb[(size_t)(mb + r) * N + n] = f2bf(f);
                }
            } else if (EPI == 2) {
                float bs = bias[n];
                float* Cf = (float*)Cout;
                #pragma unroll
                for (int r = 0; r < 4; r++)
                    Cf[(size_t)(mb + r) * N + n] =
                        acc[i][j][r] + bs + resid[(size_t)(mb + r) * N + n];
            } else if (EPI == 3) {  // transposed bf16, dst[n][m]
                float bs = bias[n];
                u16* Cb = (u16*)Cout;
                us4 pk;
                #pragma unroll
                for (int r = 0; r < 4; r++) pk[r] = f2bf(acc[i][j][r] + bs);
                *(us4*)&Cb[(size_t)n * M + mb] = pk;
            } else {                // EPI == 5: split-K atomic accumulate
                float* Cf = (float*)Cout;
                #pragma unroll
                for (int r = 0; r < 4; r++)
                    atomicAdd(&Cf[(size_t)(mb + r) * N + n], acc[i][j][r]);
            }
        }
    }
}

template<int EPI>
__global__ __launch_bounds__(256) void gemm64_kernel(const u16* __restrict__ A,
                                                     const u16* __restrict__ Wt,
                                                     const float* __restrict__ bias,
                                                     const float* __restrict__ resid,
                                                     void* __restrict__ C,
                                                     int M, int N, int Kstride, int Kloop,
                                                     float scale) {
    const u16* Az = A  + (size_t)blockIdx.z * Kloop;   // split-K offset
    const u16* Wz = Wt + (size_t)blockIdx.z * Kloop;
    gemm64_core<EPI>(Az, Wz, bias, resid, C, M, N, Kstride, Kloop, scale,
                     blockIdx.y, blockIdx.x);
}

// Fused QKV: z=0 -> q (pre-scaled), z=1 -> k, z=2 -> vT (transposed).
__global__ __launch_bounds__(256) void qkv_kernel(const u16* __restrict__ h,
        const u16* __restrict__ wqT, const u16* __restrict__ wkT, const u16* __restrict__ wvT,
        const float* __restrict__ bq, const float* __restrict__ bk, const float* __restrict__ bv,
        u16* __restrict__ q, u16* __restrict__ k, u16* __restrict__ vT) {
    int z = blockIdx.z;
    if (z == 0)      gemm64_core<0>(h, wqT, bq, nullptr, q,  MTOT, DM, DM, DM, QSCALE, blockIdx.y, blockIdx.x);
    else if (z == 1) gemm64_core<0>(h, wkT, bk, nullptr, k,  MTOT, DM, DM, DM, 1.0f,   blockIdx.y, blockIdx.x);
    else             gemm64_core<3>(h, wvT, bv, nullptr, vT, MTOT, DM, DM, DM, 1.0f,   blockIdx.y, blockIdx.x);
}

// ---------------------------------------------------------------------------
// bf16 MFMA flash attention (R6 shape: BQ=64, key-split wave = 32q x 32k,
// 52 KB LDS, high occupancy) + l computed via ones-MFMA (R7's keeper): the
// all-ones B-frag is a register constant and its D-layout (q = quad*4+r, all
// cols equal) matches Ov exactly -> no shuffles, no VALU l-adds.
// ---------------------------------------------------------------------------
__global__ __launch_bounds__(256) void attn_kernel(const u16* __restrict__ qg,
                                                   const u16* __restrict__ kg,
                                                   const u16* __restrict__ vTg,
                                                   const int* __restrict__ mask,
                                                   u16* __restrict__ ctx) {
    __shared__ __align__(16) u16 Qs[64 * 64];
    __shared__ __align__(16) u16 KV[4][64 * 64];     // [0,1]=K dbuf, [2,3]=V dbuf
    __shared__ __align__(16) u16 Ps[4][32 * 40];     // per-wave 32q x 32k, stride 40
    __shared__ __align__(16) float Msf[2][64];       // mask bias (0 / -1e9)
    __shared__ float Lp[64];                         // l partials from kh=1
    int t = threadIdx.x, ln = t & 63, w = t >> 6;
    int quad = ln >> 4, col = ln & 15;
    int qh = w >> 1, kh = w & 1;
    int bh = blockIdx.x, qb = blockIdx.y;
    int b = bh / NH, h = bh - b * NH;
    int q0 = qb * 64;
    size_t qkbase = ((size_t)b * SLEN) * DM + h * DKH;
    size_t vbase  = ((size_t)h * DKH) * MTOT + (size_t)b * SLEN;

    int sw_st = (((ln & 7) ^ (ln >> 3)) * 8);        // staging-side swizzled chunk

    // stage Q + K/V tile 0 + mask 0 (wave w stages rows 16w..16w+15)
    {
        const u16* g0 = qg + qkbase + (size_t)(q0 + 16 * w + (ln >> 3)) * DM + sw_st;
        gld16(g0,          Qs + w * 1024);
        gld16(g0 + 8 * DM, Qs + w * 1024 + 512);
        const u16* kg0 = kg + qkbase + (size_t)(16 * w + (ln >> 3)) * DM + sw_st;
        gld16(kg0,          KV[0] + w * 1024);
        gld16(kg0 + 8 * DM, KV[0] + w * 1024 + 512);
        const u16* vg0 = vTg + vbase + (size_t)(16 * w + (ln >> 3)) * MTOT + sw_st;
        gld16(vg0,            KV[2] + w * 1024);
        gld16(vg0 + 8 * MTOT, KV[2] + w * 1024 + 512);
        if (t < 64) Msf[0][t] = mask[b * SLEN + t] ? 0.f : -1e9f;
    }
    __syncthreads();

    // hoisted Q B-frags: q = qh*32 + qgi*16 + col
    bf16x8 bqf[2][2];
    #pragma unroll
    for (int qgi = 0; qgi < 2; qgi++) {
        int rq = qh * 32 + qgi * 16 + col;
        int cq = ((quad ^ (rq & 7)) * 8);
        bqf[qgi][0] = *(const bf16x8*)&Qs[rq * 64 + cq];
        bqf[qgi][1] = *(const bf16x8*)&Qs[rq * 64 + (cq ^ 32)];
    }

    // all-ones bf16 B-frag (l = P . 1 via MFMA)
    bf16x8 vones;
    #pragma unroll
    for (int i = 0; i < 8; i++) vones[i] = (short)0x3F80;

    // loop-carried prefetch pointers
    const u16* kpn = kg + qkbase + (size_t)(64 + 16 * w + (ln >> 3)) * DM + sw_st;
    const u16* vpn = vTg + vbase + (size_t)(16 * w + (ln >> 3)) * MTOT + 64 + sw_st;
    const int* mpn = mask + b * SLEN + 64 + t;

    f32x4 Ov[2][4], Lv[2];
    const f32x4 zero = {0.f, 0.f, 0.f, 0.f};
    #pragma unroll
    for (int qgi = 0; qgi < 2; qgi++) {
        Lv[qgi] = zero;
        #pragma unroll
        for (int dg = 0; dg < 4; dg++) Ov[qgi][dg] = zero;
    }
    u16* Psw = &Ps[w][0];

    for (int j0 = 0; j0 < SLEN; j0 += 64) {
        int cur = (j0 >> 6) & 1, nxt = cur ^ 1;
        if (j0 + 64 < SLEN) {
            gld16(kpn,            KV[nxt] + w * 1024);
            gld16(kpn + 8 * DM,   KV[nxt] + w * 1024 + 512);
            gld16(vpn,            KV[2 + nxt] + w * 1024);
            gld16(vpn + 8 * MTOT, KV[2 + nxt] + w * 1024 + 512);
            if (t < 64) Msf[nxt][t] = *mpn ? 0.f : -1e9f;
            kpn += 64 * DM; vpn += 64; mpn += 64;
        }

        // K A-frags: keys kh*32 + kgi*16 + col
        bf16x8 ak[2][2];
        #pragma unroll
        for (int kgi = 0; kgi < 2; kgi++) {
            int rk = kh * 32 + kgi * 16 + col;
            int ck = ((quad ^ (rk & 7)) * 8);
            ak[kgi][0] = *(const bf16x8*)&KV[cur][rk * 64 + ck];
            ak[kgi][1] = *(const bf16x8*)&KV[cur][rk * 64 + (ck ^ 32)];
        }
        // S^T tiles (key x q), mask folded into acc init; exp2; pack P
        #pragma unroll
        for (int kgi = 0; kgi < 2; kgi++) {
            f32x4 bias4 = *(const f32x4*)&Msf[cur][kh * 32 + kgi * 16 + quad * 4];
            #pragma unroll
            for (int qgi = 0; qgi < 2; qgi++) {
                f32x4 S = __builtin_amdgcn_mfma_f32_16x16x32_bf16(ak[kgi][0], bqf[qgi][0], bias4, 0, 0, 0);
                S       = __builtin_amdgcn_mfma_f32_16x16x32_bf16(ak[kgi][1], bqf[qgi][1], S,     0, 0, 0);
                float p0 = exp2f(S[0]), p1 = exp2f(S[1]);
                float p2 = exp2f(S[2]), p3 = exp2f(S[3]);
                uint2 pk;
                pk.x = pk2bf_t(p0, p1);
                pk.y = pk2bf_t(p2, p3);
                *(uint2*)&Psw[(qgi * 16 + col) * 40 + kgi * 16 + quad * 4] = pk;
            }
        }
        // P A-frags (this wave's 32 keys); l via ones-MFMA; PV
        bf16x8 ap[2];
        #pragma unroll
        for (int qgi = 0; qgi < 2; qgi++) {
            ap[qgi] = *(const bf16x8*)&Psw[(qgi * 16 + col) * 40 + quad * 8];
            Lv[qgi] = __builtin_amdgcn_mfma_f32_16x16x32_bf16(ap[qgi], vones, Lv[qgi], 0, 0, 0);
        }
        #pragma unroll
        for (int dg = 0; dg < 4; dg++) {
            int rv = dg * 16 + col;
            int cv = (((kh * 4 + quad) ^ (rv & 7)) * 8);
            bf16x8 bv = *(const bf16x8*)&KV[2 + cur][rv * 64 + cv];
            Ov[0][dg] = __builtin_amdgcn_mfma_f32_16x16x32_bf16(ap[0], bv, Ov[0][dg], 0, 0, 0);
            Ov[1][dg] = __builtin_amdgcn_mfma_f32_16x16x32_bf16(ap[1], bv, Ov[1][dg], 0, 0, 0);
        }
        __syncthreads();
    }

    // ---- cross-wave (kh) reduction through dead K/V LDS ----
    float* Osh = (float*)&KV[0][0];                  // [qh][64 d][36] fp32
    if (kh == 1) {
        #pragma unroll
        for (int qgi = 0; qgi < 2; qgi++) {
            #pragma unroll
            for (int dg = 0; dg < 4; dg++)
                *(f32x4*)&Osh[(qh * 64 + dg * 16 + col) * 36 + qgi * 16 + quad * 4] = Ov[qgi][dg];
            if (col == 0) {
                #pragma unroll
                for (int r = 0; r < 4; r++)
                    Lp[qh * 32 + qgi * 16 + quad * 4 + r] = Lv[qgi][r];
            }
        }
    }
    __syncthreads();
    if (kh == 0) {
        #pragma unroll
        for (int qgi = 0; qgi < 2; qgi++) {
            float linv[4];
            #pragma unroll
            for (int r = 0; r < 4; r++) {
                int ql = qh * 32 + qgi * 16 + quad * 4 + r;
                linv[r] = 1.0f / (Lv[qgi][r] + Lp[ql]);
            }
            #pragma unroll
            for (int dg = 0; dg < 4; dg++) {
                f32x4 oo = *(const f32x4*)&Osh[(qh * 64 + dg * 16 + col) * 36 + qgi * 16 + quad * 4];
                #pragma unroll
                for (int r = 0; r < 4; r++) {
                    int qrow = q0 + qh * 32 + qgi * 16 + quad * 4 + r;
                    ctx[qkbase + (size_t)qrow * DM + dg * 16 + col] =
                        f2bf((Ov[qgi][dg][r] + oo[r]) * linv[r]);
                }
            }
        }
    }
}

// ---------------------------------------------------------------------------
extern "C" void kernel_launch(void* const* d_in, const int* in_sizes, int n_in,
                              void* d_out, int out_size, void* d_ws, size_t ws_size,
                              hipStream_t stream) {
    const float* x    = (const float*)d_in[0];
    const int*   mask = (const int*)d_in[1];
    const float* wq   = (const float*)d_in[2];
    const float* bq   = (const float*)d_in[3];
    const float* wk   = (const float*)d_in[4];
    const float* bk   = (const float*)d_in[5];
    const float* wv   = (const float*)d_in[6];
    const float* bv   = (const float*)d_in[7];
    const float* wo   = (const float*)d_in[8];
    const float* bo   = (const float*)d_in[9];
    const float* w1   = (const float*)d_in[10];
    const float* b1   = (const float*)d_in[11];
    const float* w2   = (const float*)d_in[12];
    const float* b2   = (const float*)d_in[13];
    const float* ln1a = (const float*)d_in[14];
    const float* ln1b = (const float*)d_in[15];
    const float* ln2a = (const float*)d_in[16];
    const float* ln2b = (const float*)d_in[17];
    float* out = (float*)d_out;

    // workspace layout (bytes); ffn overlays q/k/vT/ctx (dead by FFN1)
    char* w8 = (char*)d_ws;
    u16*   ffn = (u16*)(w8 + 0);          // [4096][3072] bf16
    u16*   q   = (u16*)(w8 + 0);          // [4096][768] bf16 (pre-scaled)
    u16*   kb  = (u16*)(w8 + 6291456);
    u16*   vT  = (u16*)(w8 + 12582912);   // [768][4096] bf16
    u16*   ctx = (u16*)(w8 + 18874368);
    u16*   h   = (u16*)(w8 + 25165824);   // [4096][768] bf16
    float* x1  = (float*)(w8 + 31457280); // [4096][768] fp32
    u16*   wqT = (u16*)(w8 + 44040192);
    u16*   wkT = (u16*)(w8 + 45219840);
    u16*   wvT = (u16*)(w8 + 46399488);
    u16*   woT = (u16*)(w8 + 47579136);
    u16*   w1T = (u16*)(w8 + 48758784);   // [3072][768]
    u16*   w2T = (u16*)(w8 + 53477376);   // [768][3072]

    // 0+1. fused: h = LN1(x) AND all weights -> bf16 transposed
    prep_kernel<<<MTOT + 6912, 256, 0, stream>>>(x, h, ln1a, ln1b,
                                                 wq, wk, wv, wo, w1, w2,
                                                 wqT, wkT, wvT, woT, w1T, w2T);
    // 2. q (pre-scaled), k row-major; v transposed. 64-tiles: 2304 blocks
    qkv_kernel<<<dim3(12, 64, 3), 256, 0, stream>>>(h, wqT, wkT, wvT, bq, bk, bv, q, kb, vT);
    // 3. ctx = flash-attention (BQ=64); grid (bh, qb) for XCD K/V locality
    attn_kernel<<<dim3(BATCH * NH, SLEN / 64), 256, 0, stream>>>(q, kb, vT, mask, ctx);
    // 4. x1 = x + ctx @ wo + bo
    gemm64_kernel<2><<<dim3(12, 64), 256, 0, stream>>>(ctx, woT, bo, x, (void*)x1,
                                                       MTOT, DM, DM, DM, 1.0f);
    // 5. h = LN2(x1), fused: out = x1 + b2 (seed for FFN2 atomics)
    ln_kernel<<<MTOT, 256, 0, stream>>>(x1, h, ln2a, ln2b, b2, out);
    // 6. ffn = relu(h @ w1 + b1). 64-tiles: 3072 blocks
    gemm64_kernel<1><<<dim3(48, 64), 256, 0, stream>>>(h, w1T, b1, nullptr, (void*)ffn,
                                                       MTOT, DFF, DM, DM, 1.0f);
    // 7. out += ffn @ w2 (split-K=2, atomic). 64-tiles: 1536 blocks
    gemm64_kernel<5><<<dim3(12, 64, 2), 256, 0, stream>>>(ffn, w2T, nullptr, nullptr, (void*)out,
                                                          MTOT, DM, DFF, DFF / 2, 1.0f);
}

// Round 9
// 285.665 us; speedup vs baseline: 1.1554x; 1.1554x over previous
//
#include <hip/hip_runtime.h>
#include <math.h>

#define DM    768
#define NH    12
#define DKH   64
#define DFF   3072
#define BATCH 2
#define SLEN  2048
#define MTOT  4096
#define LNEPS 1e-6f
#define QSCALE 0.18033688011112042f   // 0.125 * log2(e): softmax in exp2 domain

typedef unsigned short u16;
typedef __attribute__((ext_vector_type(8))) short bf16x8;   // MFMA A/B frag (4 VGPRs)
typedef __attribute__((ext_vector_type(4))) float f32x4;    // MFMA C/D frag
typedef __attribute__((ext_vector_type(4))) unsigned short us4;

__device__ __forceinline__ u16 f2bf(float f) {              // RNE float->bf16
    union { float f; unsigned int u; } v; v.f = f;
    unsigned int r = v.u + 0x7FFFu + ((v.u >> 16) & 1u);
    return (u16)(r >> 16);
}

// pack two floats -> two bf16 (TRUNCATED) in one u32 via v_perm_b32
__device__ __forceinline__ unsigned pk2bf_t(float lo, float hi) {
    union { float f; unsigned u; } a, b;
    a.f = lo; b.f = hi;
    return __builtin_amdgcn_perm(b.u, a.u, 0x07060302u);
}

// async global->LDS, 16 B per lane. LDS dest = wave-uniform base + lane*16.
__device__ __forceinline__ void gld16(const void* g, void* lds) {
    __builtin_amdgcn_global_load_lds(
        (const __attribute__((address_space(1))) unsigned int*)(unsigned long long)g,
        (__attribute__((address_space(3))) unsigned int*)(unsigned int)(unsigned long long)lds,
        16, 0, 0);
}

// XCD-locality block map: dispatch round-robins wgid%8 over XCDs. Give XCD j
// the m-blocks with m%8==j, n fastest -> each A m-block is fetched by exactly
// ONE XCD (then L2-resident for all its n-blocks) instead of once per XCD.
// Requires Mb%8==0. Speed heuristic only — correctness never depends on it.
__device__ __forceinline__ void xcd_map(int id, int Nb, int& bm, int& bn) {
    int xcd = id & 7, loc = id >> 3;
    bn = loc % Nb;
    bm = (loc / Nb) * 8 + xcd;
}

// ---------------------------------------------------------------------------
// LayerNorm body: fp32 in -> bf16 out, 256 threads, 3 elems each.
// Optional fused epilogue: out2[row] = x[row] + b2 (fp32).
// ---------------------------------------------------------------------------
__device__ __forceinline__ void ln_body(const float* __restrict__ x,
                                        u16* __restrict__ out,
                                        const float* __restrict__ alpha_p,
                                        const float* __restrict__ beta_p,
                                        const float* __restrict__ b2,
                                        float* __restrict__ out2, int row) {
    const float* xr = x + (size_t)row * DM;
    int t = threadIdx.x;
    float v0 = xr[t], v1 = xr[t + 256], v2 = xr[t + 512];
    float s = v0 + v1 + v2;
    #pragma unroll
    for (int off = 32; off > 0; off >>= 1) s += __shfl_down(s, off);
    __shared__ float red[4], red2[4];
    int wv = t >> 6, ln = t & 63;
    if (ln == 0) red[wv] = s;
    __syncthreads();
    float mean = (red[0] + red[1] + red[2] + red[3]) * (1.0f / 768.0f);
    float d0 = v0 - mean, d1 = v1 - mean, d2 = v2 - mean;
    float sq = d0 * d0 + d1 * d1 + d2 * d2;
    #pragma unroll
    for (int off = 32; off > 0; off >>= 1) sq += __shfl_down(sq, off);
    if (ln == 0) red2[wv] = sq;
    __syncthreads();
    float var = (red2[0] + red2[1] + red2[2] + red2[3]) * (1.0f / 767.0f); // ddof=1
    float scale = alpha_p[0] / (sqrtf(var) + LNEPS);
    float bias = beta_p[0];
    u16* orow = out + (size_t)row * DM;
    orow[t]       = f2bf(d0 * scale + bias);
    orow[t + 256] = f2bf(d1 * scale + bias);
    orow[t + 512] = f2bf(d2 * scale + bias);
    if (out2) {
        float* o2 = out2 + (size_t)row * DM;
        o2[t]       = v0 + b2[t];
        o2[t + 256] = v1 + b2[t + 256];
        o2[t + 512] = v2 + b2[t + 512];
    }
}

__global__ __launch_bounds__(256) void ln_kernel(const float* __restrict__ x,
                                                 u16* __restrict__ out,
                                                 const float* __restrict__ alpha_p,
                                                 const float* __restrict__ beta_p,
                                                 const float* __restrict__ b2,
                                                 float* __restrict__ out2) {
    ln_body(x, out, alpha_p, beta_p, b2, out2, blockIdx.x);
}

// ---------------------------------------------------------------------------
// Weight cast+transpose body: src[R][C] fp32 -> dst[C][R] bf16, 32x32 tiles.
// ---------------------------------------------------------------------------
__device__ __forceinline__ void wcast_body(const float* __restrict__ src,
                                           u16* __restrict__ dst,
                                           int R, int C, int bx, int by) {
    __shared__ float tile[32][33];
    int t = threadIdx.x, tx = t & 31, ty = t >> 5;
    int r0 = by * 32, c0 = bx * 32;
    #pragma unroll
    for (int p = 0; p < 4; p++)
        tile[ty + p * 8][tx] = src[(size_t)(r0 + ty + p * 8) * C + c0 + tx];
    __syncthreads();
    #pragma unroll
    for (int p = 0; p < 4; p++)
        dst[(size_t)(c0 + ty + p * 8) * R + r0 + tx] = f2bf(tile[tx][ty + p * 8]);
}

// ---------------------------------------------------------------------------
// Fused prep: blocks 0..4095 = LN1 rows; rest = all six weight-cast tiles.
// ---------------------------------------------------------------------------
__global__ __launch_bounds__(256) void prep_kernel(
        const float* __restrict__ x, u16* __restrict__ h,
        const float* __restrict__ ln1a, const float* __restrict__ ln1b,
        const float* __restrict__ wq, const float* __restrict__ wk,
        const float* __restrict__ wv, const float* __restrict__ wo,
        const float* __restrict__ w1, const float* __restrict__ w2,
        u16* __restrict__ wqT, u16* __restrict__ wkT, u16* __restrict__ wvT,
        u16* __restrict__ woT, u16* __restrict__ w1T, u16* __restrict__ w2T) {
    int bid = blockIdx.x;
    if (bid < MTOT) {
        ln_body(x, h, ln1a, ln1b, nullptr, nullptr, bid);
        return;
    }
    bid -= MTOT;
    const float* src; u16* dst; int R, C, bx, by;
    if (bid < 2304) {
        int j = bid / 576, tix = bid % 576;
        R = 768; C = 768; bx = tix % 24; by = tix / 24;
        src = (j == 0) ? wq : (j == 1) ? wk : (j == 2) ? wv : wo;
        dst = (j == 0) ? wqT : (j == 1) ? wkT : (j == 2) ? wvT : woT;
    } else if (bid < 4608) {
        int tix = bid - 2304;
        R = 768; C = 3072; bx = tix % 96; by = tix / 96;
        src = w1; dst = w1T;
    } else {
        int tix = bid - 4608;
        R = 3072; C = 768; bx = tix % 24; by = tix / 24;
        src = w2; dst = w2T;
    }
    wcast_body(src, dst, R, C, bx, by);
}

// ---------------------------------------------------------------------------
// bf16 MFMA GEMM core, 128x128 tile, BK=32, double-buffered, XOR-swizzled
// LDS. 4 waves 2x2, each wave 64x64 (4x4 MFMA).
// EPI: 0 = bf16 out *scale, 1 = bf16 relu, 2 = fp32 + resid,
//      3 = bf16 transposed (dst[n][m]), 5 = fp32 atomicAdd (split-K)
// ---------------------------------------------------------------------------
template<int EPI>
__device__ __forceinline__ void gemm128_core(const u16* __restrict__ A,
                                             const u16* __restrict__ Wt,
                                             const float* __restrict__ bias,
                                             const float* __restrict__ resid,
                                             void* __restrict__ Cout,
                                             int M, int N, int Kstride, int Kloop,
                                             float scale, int bm, int bn) {
    __shared__ __align__(16) u16 As[2][128 * 32];
    __shared__ __align__(16) u16 Bs[2][128 * 32];
    int t = threadIdx.x;
    int ln = t & 63, w = t >> 6;
    int wm = w >> 1, wn = w & 1;
    int quad = ln >> 4, col = ln & 15;
    int m0 = bm * 128, n0 = bn * 128;

    f32x4 acc[4][4];
    const f32x4 zero = {0.f, 0.f, 0.f, 0.f};
    #pragma unroll
    for (int i = 0; i < 4; i++)
        #pragma unroll
        for (int j = 0; j < 4; j++) acc[i][j] = zero;

    int st_ch = (((ln & 3) ^ ((ln >> 3) & 3))) * 8;
    const u16* Ag = A  + (size_t)(m0 + 32 * w + (ln >> 2)) * Kstride + st_ch;
    const u16* Bg = Wt + (size_t)(n0 + 32 * w + (ln >> 2)) * Kstride + st_ch;

    gld16(Ag,                As[0] + w * 1024);
    gld16(Ag + 16 * Kstride, As[0] + w * 1024 + 512);
    gld16(Bg,                Bs[0] + w * 1024);
    gld16(Bg + 16 * Kstride, Bs[0] + w * 1024 + 512);
    __syncthreads();

    int rch = (quad ^ ((col >> 1) & 3)) * 8;

    for (int k0 = 0; k0 < Kloop; k0 += 32) {
        int cur = (k0 >> 5) & 1, nxt = cur ^ 1;
        if (k0 + 32 < Kloop) {
            gld16(Ag + k0 + 32,                As[nxt] + w * 1024);
            gld16(Ag + k0 + 32 + 16 * Kstride, As[nxt] + w * 1024 + 512);
            gld16(Bg + k0 + 32,                Bs[nxt] + w * 1024);
            gld16(Bg + k0 + 32 + 16 * Kstride, Bs[nxt] + w * 1024 + 512);
        }
        bf16x8 af[4], bfr[4];
        #pragma unroll
        for (int i = 0; i < 4; i++)
            af[i] = *(const bf16x8*)&As[cur][(wm * 64 + i * 16 + col) * 32 + rch];
        #pragma unroll
        for (int j = 0; j < 4; j++)
            bfr[j] = *(const bf16x8*)&Bs[cur][(wn * 64 + j * 16 + col) * 32 + rch];
        #pragma unroll
        for (int i = 0; i < 4; i++)
            #pragma unroll
            for (int j = 0; j < 4; j++)
                acc[i][j] = __builtin_amdgcn_mfma_f32_16x16x32_bf16(af[i], bfr[j], acc[i][j], 0, 0, 0);
        __syncthreads();
    }

    #pragma unroll
    for (int i = 0; i < 4; i++) {
        int mb = m0 + wm * 64 + i * 16 + quad * 4;
        #pragma unroll
        for (int j = 0; j < 4; j++) {
            int n = n0 + wn * 64 + j * 16 + col;
            if (EPI == 0 || EPI == 1) {
                float bs = bias[n];
                u16* Cb = (u16*)Cout;
                #pragma unroll
                for (int r = 0; r < 4; r++) {
                    float f = (acc[i][j][r] + bs) * ((EPI == 0) ? scale : 1.0f);
                    if (EPI == 1) f = fmaxf(f, 0.f);
                    Cb[(size_t)(mb + r) * N + n] = f2bf(f);
                }
            } else if (EPI == 2) {
                float bs = bias[n];
                float* Cf = (float*)Cout;
                #pragma unroll
                for (int r = 0; r < 4; r++)
                    Cf[(size_t)(mb + r) * N + n] =
                        acc[i][j][r] + bs + resid[(size_t)(mb + r) * N + n];
            } else if (EPI == 3) {
                float bs = bias[n];
                u16* Cb = (u16*)Cout;
                us4 pk;
                #pragma unroll
                for (int r = 0; r < 4; r++) pk[r] = f2bf(acc[i][j][r] + bs);
                *(us4*)&Cb[(size_t)n * M + mb] = pk;
            } else {
                float* Cf = (float*)Cout;
                #pragma unroll
                for (int r = 0; r < 4; r++)
                    atomicAdd(&Cf[(size_t)(mb + r) * N + n], acc[i][j][r]);
            }
        }
    }
}

// 1D-x grid, XCD-mapped; z = split-K slice.
template<int EPI>
__global__ __launch_bounds__(256) void gemm_kernel(const u16* __restrict__ A,
                                                   const u16* __restrict__ Wt,
                                                   const float* __restrict__ bias,
                                                   const float* __restrict__ resid,
                                                   void* __restrict__ C,
                                                   int M, int N, int Kstride, int Kloop,
                                                   float scale, int Nb) {
    const u16* Az = A  + (size_t)blockIdx.z * Kloop;
    const u16* Wz = Wt + (size_t)blockIdx.z * Kloop;
    int bm, bn;
    xcd_map(blockIdx.x, Nb, bm, bn);
    gemm128_core<EPI>(Az, Wz, bias, resid, C, M, N, Kstride, Kloop, scale, bm, bn);
}

// Fused QKV: z=0 -> q (pre-scaled), z=1 -> k, z=2 -> vT. 1D-x XCD-mapped.
__global__ __launch_bounds__(256) void qkv_kernel(const u16* __restrict__ h,
        const u16* __restrict__ wqT, const u16* __restrict__ wkT, const u16* __restrict__ wvT,
        const float* __restrict__ bq, const float* __restrict__ bk, const float* __restrict__ bv,
        u16* __restrict__ q, u16* __restrict__ k, u16* __restrict__ vT) {
    int z = blockIdx.z;
    int bm, bn;
    xcd_map(blockIdx.x, 6, bm, bn);
    if (z == 0)      gemm128_core<0>(h, wqT, bq, nullptr, q,  MTOT, DM, DM, DM, QSCALE, bm, bn);
    else if (z == 1) gemm128_core<0>(h, wkT, bk, nullptr, k,  MTOT, DM, DM, DM, 1.0f,   bm, bn);
    else             gemm128_core<3>(h, wvT, bv, nullptr, vT, MTOT, DM, DM, DM, 1.0f,   bm, bn);
}

// ---------------------------------------------------------------------------
// 64x64-tile GEMM (narrow Wo). EPI=2 path. 1D-x XCD-mapped (Mb=64, Nb=12).
// ---------------------------------------------------------------------------
template<int EPI>
__global__ __launch_bounds__(256) void gemm64_kernel(const u16* __restrict__ A,
                                                     const u16* __restrict__ Wt,
                                                     const float* __restrict__ bias,
                                                     const float* __restrict__ resid,
                                                     void* __restrict__ Cout,
                                                     int M, int N, int Kstride, int Kloop,
                                                     int Nb) {
    __shared__ __align__(16) u16 As[2][64 * 32];
    __shared__ __align__(16) u16 Bs[2][64 * 32];
    int t = threadIdx.x, ln = t & 63, w = t >> 6;
    int wm = w >> 1, wn = w & 1;
    int quad = ln >> 4, col = ln & 15;
    int bm, bn;
    xcd_map(blockIdx.x, Nb, bm, bn);
    int m0 = bm * 64, n0 = bn * 64;

    f32x4 acc[2][2];
    const f32x4 zero = {0.f, 0.f, 0.f, 0.f};
    #pragma unroll
    for (int i = 0; i < 2; i++)
        #pragma unroll
        for (int j = 0; j < 2; j++) acc[i][j] = zero;

    int st_ch = (((ln & 3) ^ ((ln >> 3) & 3))) * 8;
    const u16* Ag = A  + (size_t)(m0 + 16 * w + (ln >> 2)) * Kstride + st_ch;
    const u16* Bg = Wt + (size_t)(n0 + 16 * w + (ln >> 2)) * Kstride + st_ch;
    gld16(Ag, As[0] + w * 512);
    gld16(Bg, Bs[0] + w * 512);
    __syncthreads();

    int rch = (quad ^ ((col >> 1) & 3)) * 8;

    for (int k0 = 0; k0 < Kloop; k0 += 32) {
        int cur = (k0 >> 5) & 1, nxt = cur ^ 1;
        if (k0 + 32 < Kloop) {
            gld16(Ag + k0 + 32, As[nxt] + w * 512);
            gld16(Bg + k0 + 32, Bs[nxt] + w * 512);
        }
        bf16x8 af[2], bfr[2];
        #pragma unroll
        for (int i = 0; i < 2; i++)
            af[i] = *(const bf16x8*)&As[cur][(wm * 32 + i * 16 + col) * 32 + rch];
        #pragma unroll
        for (int j = 0; j < 2; j++)
            bfr[j] = *(const bf16x8*)&Bs[cur][(wn * 32 + j * 16 + col) * 32 + rch];
        #pragma unroll
        for (int i = 0; i < 2; i++)
            #pragma unroll
            for (int j = 0; j < 2; j++)
                acc[i][j] = __builtin_amdgcn_mfma_f32_16x16x32_bf16(af[i], bfr[j], acc[i][j], 0, 0, 0);
        __syncthreads();
    }

    #pragma unroll
    for (int i = 0; i < 2; i++) {
        int mb = m0 + wm * 32 + i * 16 + quad * 4;
        #pragma unroll
        for (int j = 0; j < 2; j++) {
            int n = n0 + wn * 32 + j * 16 + col;
            float bs = bias[n];
            float* Cf = (float*)Cout;
            #pragma unroll
            for (int r = 0; r < 4; r++)
                Cf[(size_t)(mb + r) * N + n] =
                    acc[i][j][r] + bs + resid[(size_t)(mb + r) * N + n];
        }
    }
}

// ---------------------------------------------------------------------------
// bf16 MFMA flash attention (BQ=64, key-split wave = 32q x 32k, ones-MFMA l).
// ---------------------------------------------------------------------------
__global__ __launch_bounds__(256) void attn_kernel(const u16* __restrict__ qg,
                                                   const u16* __restrict__ kg,
                                                   const u16* __restrict__ vTg,
                                                   const int* __restrict__ mask,
                                                   u16* __restrict__ ctx) {
    __shared__ __align__(16) u16 Qs[64 * 64];
    __shared__ __align__(16) u16 KV[4][64 * 64];     // [0,1]=K dbuf, [2,3]=V dbuf
    __shared__ __align__(16) u16 Ps[4][32 * 40];     // per-wave 32q x 32k, stride 40
    __shared__ __align__(16) float Msf[2][64];       // mask bias (0 / -1e9)
    __shared__ float Lp[64];                         // l partials from kh=1
    int t = threadIdx.x, ln = t & 63, w = t >> 6;
    int quad = ln >> 4, col = ln & 15;
    int qh = w >> 1, kh = w & 1;
    int bh = blockIdx.x, qb = blockIdx.y;
    int b = bh / NH, h = bh - b * NH;
    int q0 = qb * 64;
    size_t qkbase = ((size_t)b * SLEN) * DM + h * DKH;
    size_t vbase  = ((size_t)h * DKH) * MTOT + (size_t)b * SLEN;

    int sw_st = (((ln & 7) ^ (ln >> 3)) * 8);        // staging-side swizzled chunk

    // stage Q + K/V tile 0 + mask 0 (wave w stages rows 16w..16w+15)
    {
        const u16* g0 = qg + qkbase + (size_t)(q0 + 16 * w + (ln >> 3)) * DM + sw_st;
        gld16(g0,          Qs + w * 1024);
        gld16(g0 + 8 * DM, Qs + w * 1024 + 512);
        const u16* kg0 = kg + qkbase + (size_t)(16 * w + (ln >> 3)) * DM + sw_st;
        gld16(kg0,          KV[0] + w * 1024);
        gld16(kg0 + 8 * DM, KV[0] + w * 1024 + 512);
        const u16* vg0 = vTg + vbase + (size_t)(16 * w + (ln >> 3)) * MTOT + sw_st;
        gld16(vg0,            KV[2] + w * 1024);
        gld16(vg0 + 8 * MTOT, KV[2] + w * 1024 + 512);
        if (t < 64) Msf[0][t] = mask[b * SLEN + t] ? 0.f : -1e9f;
    }
    __syncthreads();

    // hoisted Q B-frags: q = qh*32 + qgi*16 + col
    bf16x8 bqf[2][2];
    #pragma unroll
    for (int qgi = 0; qgi < 2; qgi++) {
        int rq = qh * 32 + qgi * 16 + col;
        int cq = ((quad ^ (rq & 7)) * 8);
        bqf[qgi][0] = *(const bf16x8*)&Qs[rq * 64 + cq];
        bqf[qgi][1] = *(const bf16x8*)&Qs[rq * 64 + (cq ^ 32)];
    }

    // all-ones bf16 B-frag (l = P . 1 via MFMA)
    bf16x8 vones;
    #pragma unroll
    for (int i = 0; i < 8; i++) vones[i] = (short)0x3F80;

    // loop-carried prefetch pointers
    const u16* kpn = kg + qkbase + (size_t)(64 + 16 * w + (ln >> 3)) * DM + sw_st;
    const u16* vpn = vTg + vbase + (size_t)(16 * w + (ln >> 3)) * MTOT + 64 + sw_st;
    const int* mpn = mask + b * SLEN + 64 + t;

    f32x4 Ov[2][4], Lv[2];
    const f32x4 zero = {0.f, 0.f, 0.f, 0.f};
    #pragma unroll
    for (int qgi = 0; qgi < 2; qgi++) {
        Lv[qgi] = zero;
        #pragma unroll
        for (int dg = 0; dg < 4; dg++) Ov[qgi][dg] = zero;
    }
    u16* Psw = &Ps[w][0];

    for (int j0 = 0; j0 < SLEN; j0 += 64) {
        int cur = (j0 >> 6) & 1, nxt = cur ^ 1;
        if (j0 + 64 < SLEN) {
            gld16(kpn,            KV[nxt] + w * 1024);
            gld16(kpn + 8 * DM,   KV[nxt] + w * 1024 + 512);
            gld16(vpn,            KV[2 + nxt] + w * 1024);
            gld16(vpn + 8 * MTOT, KV[2 + nxt] + w * 1024 + 512);
            if (t < 64) Msf[nxt][t] = *mpn ? 0.f : -1e9f;
            kpn += 64 * DM; vpn += 64; mpn += 64;
        }

        // K A-frags: keys kh*32 + kgi*16 + col
        bf16x8 ak[2][2];
        #pragma unroll
        for (int kgi = 0; kgi < 2; kgi++) {
            int rk = kh * 32 + kgi * 16 + col;
            int ck = ((quad ^ (rk & 7)) * 8);
            ak[kgi][0] = *(const bf16x8*)&KV[cur][rk * 64 + ck];
            ak[kgi][1] = *(const bf16x8*)&KV[cur][rk * 64 + (ck ^ 32)];
        }
        // S^T tiles (key x q), mask folded into acc init; exp2; pack P
        #pragma unroll
        for (int kgi = 0; kgi < 2; kgi++) {
            f32x4 bias4 = *(const f32x4*)&Msf[cur][kh * 32 + kgi * 16 + quad * 4];
            #pragma unroll
            for (int qgi = 0; qgi < 2; qgi++) {
                f32x4 S = __builtin_amdgcn_mfma_f32_16x16x32_bf16(ak[kgi][0], bqf[qgi][0], bias4, 0, 0, 0);
                S       = __builtin_amdgcn_mfma_f32_16x16x32_bf16(ak[kgi][1], bqf[qgi][1], S,     0, 0, 0);
                float p0 = exp2f(S[0]), p1 = exp2f(S[1]);
                float p2 = exp2f(S[2]), p3 = exp2f(S[3]);
                uint2 pk;
                pk.x = pk2bf_t(p0, p1);
                pk.y = pk2bf_t(p2, p3);
                *(uint2*)&Psw[(qgi * 16 + col) * 40 + kgi * 16 + quad * 4] = pk;
            }
        }
        // P A-frags (this wave's 32 keys); l via ones-MFMA; PV
        bf16x8 ap[2];
        #pragma unroll
        for (int qgi = 0; qgi < 2; qgi++) {
            ap[qgi] = *(const bf16x8*)&Psw[(qgi * 16 + col) * 40 + quad * 8];
            Lv[qgi] = __builtin_amdgcn_mfma_f32_16x16x32_bf16(ap[qgi], vones, Lv[qgi], 0, 0, 0);
        }
        #pragma unroll
        for (int dg = 0; dg < 4; dg++) {
            int rv = dg * 16 + col;
            int cv = (((kh * 4 + quad) ^ (rv & 7)) * 8);
            bf16x8 bv = *(const bf16x8*)&KV[2 + cur][rv * 64 + cv];
            Ov[0][dg] = __builtin_amdgcn_mfma_f32_16x16x32_bf16(ap[0], bv, Ov[0][dg], 0, 0, 0);
            Ov[1][dg] = __builtin_amdgcn_mfma_f32_16x16x32_bf16(ap[1], bv, Ov[1][dg], 0, 0, 0);
        }
        __syncthreads();
    }

    // ---- cross-wave (kh) reduction through dead K/V LDS ----
    float* Osh = (float*)&KV[0][0];                  // [qh][64 d][36] fp32
    if (kh == 1) {
        #pragma unroll
        for (int qgi = 0; qgi < 2; qgi++) {
            #pragma unroll
            for (int dg = 0; dg < 4; dg++)
                *(f32x4*)&Osh[(qh * 64 + dg * 16 + col) * 36 + qgi * 16 + quad * 4] = Ov[qgi][dg];
            if (col == 0) {
                #pragma unroll
                for (int r = 0; r < 4; r++)
                    Lp[qh * 32 + qgi * 16 + quad * 4 + r] = Lv[qgi][r];
            }
        }
    }
    __syncthreads();
    if (kh == 0) {
        #pragma unroll
        for (int qgi = 0; qgi < 2; qgi++) {
            float linv[4];
            #pragma unroll
            for (int r = 0; r < 4; r++) {
                int ql = qh * 32 + qgi * 16 + quad * 4 + r;
                linv[r] = 1.0f / (Lv[qgi][r] + Lp[ql]);
            }
            #pragma unroll
            for (int dg = 0; dg < 4; dg++) {
                f32x4 oo = *(const f32x4*)&Osh[(qh * 64 + dg * 16 + col) * 36 + qgi * 16 + quad * 4];
                #pragma unroll
                for (int r = 0; r < 4; r++) {
                    int qrow = q0 + qh * 32 + qgi * 16 + quad * 4 + r;
                    ctx[qkbase + (size_t)qrow * DM + dg * 16 + col] =
                        f2bf((Ov[qgi][dg][r] + oo[r]) * linv[r]);
                }
            }
        }
    }
}

// ---------------------------------------------------------------------------
extern "C" void kernel_launch(void* const* d_in, const int* in_sizes, int n_in,
                              void* d_out, int out_size, void* d_ws, size_t ws_size,
                              hipStream_t stream) {
    const float* x    = (const float*)d_in[0];
    const int*   mask = (const int*)d_in[1];
    const float* wq   = (const float*)d_in[2];
    const float* bq   = (const float*)d_in[3];
    const float* wk   = (const float*)d_in[4];
    const float* bk   = (const float*)d_in[5];
    const float* wv   = (const float*)d_in[6];
    const float* bv   = (const float*)d_in[7];
    const float* wo   = (const float*)d_in[8];
    const float* bo   = (const float*)d_in[9];
    const float* w1   = (const float*)d_in[10];
    const float* b1   = (const float*)d_in[11];
    const float* w2   = (const float*)d_in[12];
    const float* b2   = (const float*)d_in[13];
    const float* ln1a = (const float*)d_in[14];
    const float* ln1b = (const float*)d_in[15];
    const float* ln2a = (const float*)d_in[16];
    const float* ln2b = (const float*)d_in[17];
    float* out = (float*)d_out;

    // workspace layout (bytes); ffn overlays q/k/vT/ctx (dead by FFN1)
    char* w8 = (char*)d_ws;
    u16*   ffn = (u16*)(w8 + 0);          // [4096][3072] bf16
    u16*   q   = (u16*)(w8 + 0);          // [4096][768] bf16 (pre-scaled)
    u16*   kb  = (u16*)(w8 + 6291456);
    u16*   vT  = (u16*)(w8 + 12582912);   // [768][4096] bf16
    u16*   ctx = (u16*)(w8 + 18874368);
    u16*   h   = (u16*)(w8 + 25165824);   // [4096][768] bf16
    float* x1  = (float*)(w8 + 31457280); // [4096][768] fp32
    u16*   wqT = (u16*)(w8 + 44040192);
    u16*   wkT = (u16*)(w8 + 45219840);
    u16*   wvT = (u16*)(w8 + 46399488);
    u16*   woT = (u16*)(w8 + 47579136);
    u16*   w1T = (u16*)(w8 + 48758784);   // [3072][768]
    u16*   w2T = (u16*)(w8 + 53477376);   // [768][3072]

    // 0+1. fused: h = LN1(x) AND all weights -> bf16 transposed
    prep_kernel<<<MTOT + 6912, 256, 0, stream>>>(x, h, ln1a, ln1b,
                                                 wq, wk, wv, wo, w1, w2,
                                                 wqT, wkT, wvT, woT, w1T, w2T);
    // 2. q (pre-scaled), k, vT. 128-tiles, XCD-mapped 1D grid (Mb=32, Nb=6)
    qkv_kernel<<<dim3(192, 1, 3), 256, 0, stream>>>(h, wqT, wkT, wvT, bq, bk, bv, q, kb, vT);
    // 3. ctx = flash-attention (BQ=64); grid (bh, qb) for XCD K/V locality
    attn_kernel<<<dim3(BATCH * NH, SLEN / 64), 256, 0, stream>>>(q, kb, vT, mask, ctx);
    // 4. x1 = x + ctx @ wo + bo. 64-tiles, XCD-mapped (Mb=64, Nb=12)
    gemm64_kernel<2><<<768, 256, 0, stream>>>(ctx, woT, bo, x, (void*)x1,
                                              MTOT, DM, DM, DM, 12);
    // 5. h = LN2(x1), fused: out = x1 + b2 (seed for FFN2 atomics)
    ln_kernel<<<MTOT, 256, 0, stream>>>(x1, h, ln2a, ln2b, b2, out);
    // 6. ffn = relu(h @ w1 + b1). 128-tiles, XCD-mapped (Mb=32, Nb=24)
    gemm_kernel<1><<<768, 256, 0, stream>>>(h, w1T, b1, nullptr, (void*)ffn,
                                            MTOT, DFF, DM, DM, 1.0f, 24);
    // 7. out += ffn @ w2 (split-K=2, atomic). 128-tiles, XCD-mapped (Mb=32, Nb=6)
    gemm_kernel<5><<<dim3(192, 1, 2), 256, 0, stream>>>(ffn, w2T, nullptr, nullptr, (void*)out,
                                                        MTOT, DM, DFF, DFF / 2, 1.0f, 6);
}